// Round 6
// baseline (2463.646 us; speedup 1.0000x reference)
//
#include <hip/hip_runtime.h>
#include <math.h>

// Problem constants
constexpr int B_  = 64;
constexpr int S_  = 512;
constexpr int H_  = 768;
constexpr int H2_ = 1536;   // 2H
constexpr int G3_ = 2304;   // 3H
constexpr int OP_ = 18;
constexpr int C_  = 24;
constexpr int M_  = 16;
constexpr int E_  = 8;
constexpr int A_  = 3;
constexpr int K_  = 48;     // C+M+E
constexpr int HH_ = 384;    // H/2

// ---------------------------------------------------------------------------
// GEMM core: ONE WAVE computes 64 rows x 32 cols of C = A @ W^T (partial over
// a K-range of nkt*32), writing raw partials to Pout[r*ldP + c].
// - Thread t stages act row t (32 K-floats); weight: thread t stages the
//   (t&31)-th col's K-half (t>>5)  -> all LDS writes <=2-way (free).
// - Register prefetch of tile kt+1 issued before tile kt's compute.
// - micro-tile 8x4: 32 FMA per 3 broadcast LDS b128 reads.
// ---------------------------------------------------------------------------
__device__ __forceinline__ void gemm_core32(
    const float* __restrict__ asrc,     // act row (= row tid), null -> zeros
    const float* __restrict__ wsrc,     // weight ptr: col (tid&31), + (tid>>5)*16
    int k0base, int nkt,
    float* __restrict__ Pout, int ldP)
{
    __shared__ float As[32][68];
    __shared__ float Ws[32][36];
    const int tid = threadIdx.x;         // 0..63
    const int c0 = (tid & 7) * 4, r0 = (tid >> 3) * 8;
    const int wk = (tid >> 5) * 16;      // K-offset this thread stages for W
    const int wc = tid & 31;             // weight col this thread stages

    float acc[8][4];
    #pragma unroll
    for (int a = 0; a < 8; ++a)
        #pragma unroll
        for (int b = 0; b < 4; ++b) acc[a][b] = 0.f;

    float4 ra[8], rw[4], ra2[8], rw2[4];
    const float4 z4 = make_float4(0.f, 0.f, 0.f, 0.f);

    #pragma unroll
    for (int c = 0; c < 8; ++c)
        ra[c] = asrc ? *(const float4*)(asrc + k0base + c * 4) : z4;
    #pragma unroll
    for (int c = 0; c < 4; ++c)
        rw[c] = *(const float4*)(wsrc + k0base + c * 4);

    for (int kt = 0; kt < nkt; ++kt) {
        __syncthreads();
        #pragma unroll
        for (int c = 0; c < 8; ++c) {
            As[c * 4 + 0][tid] = ra[c].x; As[c * 4 + 1][tid] = ra[c].y;
            As[c * 4 + 2][tid] = ra[c].z; As[c * 4 + 3][tid] = ra[c].w;
        }
        #pragma unroll
        for (int c = 0; c < 4; ++c) {
            Ws[wk + c * 4 + 0][wc] = rw[c].x; Ws[wk + c * 4 + 1][wc] = rw[c].y;
            Ws[wk + c * 4 + 2][wc] = rw[c].z; Ws[wk + c * 4 + 3][wc] = rw[c].w;
        }
        if (kt + 1 < nkt) {
            const int k0 = k0base + (kt + 1) * 32;
            #pragma unroll
            for (int c = 0; c < 8; ++c)
                ra2[c] = asrc ? *(const float4*)(asrc + k0 + c * 4) : z4;
            #pragma unroll
            for (int c = 0; c < 4; ++c)
                rw2[c] = *(const float4*)(wsrc + k0 + c * 4);
        }
        __syncthreads();

        #pragma unroll 4
        for (int kk = 0; kk < 32; ++kk) {
            float4 a0 = *(const float4*)&As[kk][r0];
            float4 a1 = *(const float4*)&As[kk][r0 + 4];
            float4 w0 = *(const float4*)&Ws[kk][c0];
            float av[8] = {a0.x, a0.y, a0.z, a0.w, a1.x, a1.y, a1.z, a1.w};
            float wv[4] = {w0.x, w0.y, w0.z, w0.w};
            #pragma unroll
            for (int rr = 0; rr < 8; ++rr)
                #pragma unroll
                for (int cc = 0; cc < 4; ++cc)
                    acc[rr][cc] += av[rr] * wv[cc];
        }
        #pragma unroll
        for (int c = 0; c < 8; ++c) ra[c] = ra2[c];
        #pragma unroll
        for (int c = 0; c < 4; ++c) rw[c] = rw2[c];
    }

    #pragma unroll
    for (int rr = 0; rr < 8; ++rr) {
        *(float4*)(Pout + (long)(r0 + rr) * ldP + c0) =
            make_float4(acc[rr][0], acc[rr][1], acc[rr][2], acc[rr][3]);
    }
}

// ---------------------------------------------------------------------------
// GRU dual GEMM: grid (144, 12). bx<72 -> gi cols (x @ Wih^T), else gh cols.
// K=768 split 12 ways (64 each, nkt=2). Optional _pick row-gather on x side.
// ---------------------------------------------------------------------------
__global__ __launch_bounds__(64) void k_gru_gemm12(
    const float* __restrict__ x, long ldx, int pickmode,
    const int* __restrict__ gopd, int i, int jm1,
    const float* __restrict__ pcb, const float* __restrict__ pnb,
    const float* __restrict__ prevb,
    const float* __restrict__ h, long ldh,
    const float* __restrict__ Wih, const float* __restrict__ Whh,
    float* __restrict__ P)
{
    const int tid = threadIdx.x;
    const int bx = blockIdx.x;
    const int kz = blockIdx.y;
    const bool hside = bx >= 72;
    const int n0 = (bx % 72) * 32;

    const float* s;
    if (hside) s = h + (long)tid * ldh;
    else if (!pickmode) s = x + (long)tid * ldx;
    else {
        int idx = gopd[(tid * E_ + i) * A_ + jm1];
        if (idx < C_)            s = pcb + (long)idx * H_;
        else if (idx < C_ + M_)  s = pnb + ((long)tid * M_ + (idx - C_)) * H_;
        else                     s = prevb + ((long)tid * E_ + (idx - C_ - M_)) * H_;
    }
    const float* wsrc = (hside ? Whh : Wih) + (long)(n0 + (tid & 31)) * 768 + (tid >> 5) * 16;
    float* Pout = P + (long)kz * 64 * 4608 + (hside ? 2304 : 0) + n0;
    gemm_core32(s, wsrc, kz * 64, 2, Pout, 4608);
}

// Sum 12 K-partials, add biases, apply GRU gates: hnew = (1-z)*n + z*h
__global__ void k_gru_finish12(const float* __restrict__ P,
                               const float* __restrict__ h, long ldh,
                               const float* __restrict__ bih, const float* __restrict__ bhh,
                               float* __restrict__ hnew)
{
    int t = blockIdx.x * 256 + threadIdx.x;       // 64*768
    int b = t / 768, c = t - b * 768;
    const float* Pb = P + (long)b * 4608;
    float ir = bih[c], iz = bih[768 + c], in_ = bih[1536 + c];
    float hr = bhh[c], hz = bhh[768 + c], hn  = bhh[1536 + c];
    #pragma unroll
    for (int z = 0; z < 12; ++z) {
        const float* q = Pb + (long)z * 64 * 4608;
        ir += q[c];        iz += q[768 + c];  in_ += q[1536 + c];
        hr += q[2304 + c]; hz += q[3072 + c]; hn  += q[3840 + c];
    }
    float r  = 1.f / (1.f + expf(-(ir + hr)));
    float z_ = 1.f / (1.f + expf(-(iz + hz)));
    float n  = tanhf(in_ + r * hn);
    float hp = h[(long)b * ldh + c];
    hnew[t] = (1.f - z_) * n + z_ * hp;
}

// ---------------------------------------------------------------------------
// Generic projection GEMM (partials): grid (ncolblk32, nrowblk, KS=6)
// ---------------------------------------------------------------------------
__global__ __launch_bounds__(64) void k_proj_gemm(
    const float* __restrict__ A, long lda, const int* __restrict__ gidx, int Mm,
    const float* __restrict__ W, int wld, int nkt,
    float* __restrict__ P, int ldP, int Mpad)
{
    const int tid = threadIdx.x;
    const int n0 = blockIdx.x * 32;
    const int rb = blockIdx.y * 64;
    const int kz = blockIdx.z;
    int r = rb + tid;
    const float* asrc = nullptr;
    if (r < Mm) asrc = gidx ? (A + (long)gidx[r] * lda) : (A + (long)r * lda);
    const float* wsrc = W + (long)(n0 + (tid & 31)) * wld + (tid >> 5) * 16;
    float* Pout = P + ((long)kz * Mpad + rb) * ldP + n0;
    gemm_core32(asrc, wsrc, kz * nkt * 32, nkt, Pout, ldP);
}

// Sum KS partials + bias, then LayerNorm the 768-wide row.
__global__ void k_ln_finish(const float* __restrict__ P, int ldP, int Mpad, int KS,
                            const float* __restrict__ bias, const float* __restrict__ g,
                            const float* __restrict__ be,
                            float* __restrict__ out, long ldout)
{
    int row = blockIdx.x, tid = threadIdx.x;
    __shared__ float red[256];
    float v[3];
    #pragma unroll
    for (int it = 0; it < 3; ++it) {
        int c2 = tid + it * 256;
        float s = bias[c2];
        for (int z = 0; z < KS; ++z) s += P[((long)z * Mpad + row) * ldP + c2];
        v[it] = s;
    }
    float s = v[0] + v[1] + v[2];
    red[tid] = s; __syncthreads();
    for (int o = 128; o > 0; o >>= 1) { if (tid < o) red[tid] += red[tid + o]; __syncthreads(); }
    float mu = red[0] / 768.f;
    __syncthreads();
    float vv = 0.f;
    #pragma unroll
    for (int it = 0; it < 3; ++it) { float d = v[it] - mu; vv += d * d; }
    red[tid] = vv; __syncthreads();
    for (int o = 128; o > 0; o >>= 1) { if (tid < o) red[tid] += red[tid + o]; __syncthreads(); }
    float inv = 1.f / sqrtf(red[0] / 768.f + 1e-5f);
    #pragma unroll
    for (int it = 0; it < 3; ++it) {
        int c2 = tid + it * 256;
        out[(long)row * ldout + c2] = (v[it] - mu) * inv * g[c2] + be[c2];
    }
}

// Fused op head: hid = relu(cv@W1^T+b1) (384), logits = hid@W2^T+b2 (18)
__global__ __launch_bounds__(256) void k_ophead_fused(
    const float* __restrict__ cv,
    const float* __restrict__ W1, const float* __restrict__ b1,
    const float* __restrict__ W2, const float* __restrict__ b2,
    float* __restrict__ op_out, int i)
{
    int b = blockIdx.x, tid = threadIdx.x;
    __shared__ float xs[768];
    __shared__ float hs[384];
    const float* xr = cv + (long)b * 768;
    #pragma unroll
    for (int it = 0; it < 3; ++it) xs[tid + it * 256] = xr[tid + it * 256];
    __syncthreads();

    for (int c = tid; c < 384; c += 256) {
        const float* wr = W1 + (long)c * 768;
        float acc = 0.f;
        #pragma unroll 8
        for (int k = 0; k < 768; k += 4) {
            float4 xv = *(const float4*)&xs[k];
            float4 wv = *(const float4*)(wr + k);
            acc += xv.x * wv.x + xv.y * wv.y + xv.z * wv.z + xv.w * wv.w;
        }
        hs[c] = fmaxf(acc + b1[c], 0.f);
    }
    __syncthreads();

    int c = tid >> 3, g = tid & 7;
    float acc = 0.f;
    if (c < OP_) {
        const float* wr = W2 + (long)c * HH_;
        #pragma unroll
        for (int t = 0; t < 12; ++t) {
            int k = (g + 8 * t) * 4;
            float4 xv = *(const float4*)&hs[k];
            float4 wv = *(const float4*)(wr + k);
            acc += xv.x * wv.x + xv.y * wv.y + xv.z * wv.z + xv.w * wv.w;
        }
    }
    acc += __shfl_xor(acc, 1);
    acc += __shfl_xor(acc, 2);
    acc += __shfl_xor(acc, 4);
    if (c < OP_ && g == 0)
        op_out[((long)b * E_ + i) * OP_ + c] = acc + b2[c];
}

// ---------------------------------------------------------------------------
// Fused od head: MLP1(relu) + MLP2 + logit write + argmax + prev cond-update.
// If do_final: also pred = pick(oidx) and the post-loop final prev update
// (replaces the separate k_final_update kernel).
// ---------------------------------------------------------------------------
__global__ __launch_bounds__(256) void k_odhead(
    const float* __restrict__ hx1,
    const float* __restrict__ W1, const float* __restrict__ b1,
    const float* __restrict__ W2, const float* __restrict__ b2,
    float* __restrict__ od_base, long ldl,
    float* __restrict__ prev, int i,
    const float* __restrict__ pcb, const float* __restrict__ pnb,
    int do_final)
{
    int b = blockIdx.x, tid = threadIdx.x;
    __shared__ float xs[768];
    __shared__ float ps[768];
    __shared__ float hidL[24];
    __shared__ float lg[48];
    __shared__ float red[256];
    __shared__ int s_oidx;

    const float* xr = hx1 + (long)b * 768;
    #pragma unroll
    for (int it = 0; it < 3; ++it) xs[tid + it * 256] = xr[tid + it * 256];
    __syncthreads();

    int c = tid >> 3, g = tid & 7;
    float acc = 0.f;
    if (c < 24) {
        const float* wr = W1 + (long)c * 768;
        #pragma unroll
        for (int t = 0; t < 24; ++t) {
            int k = (g + 8 * t) * 4;
            float4 xv = *(const float4*)&xs[k];
            float4 wv = *(const float4*)(wr + k);
            acc += xv.x * wv.x + xv.y * wv.y + xv.z * wv.z + xv.w * wv.w;
        }
    }
    acc += __shfl_xor(acc, 1);
    acc += __shfl_xor(acc, 2);
    acc += __shfl_xor(acc, 4);
    if (c < 24 && g == 0) hidL[c] = fmaxf(acc + b1[c], 0.f);
    __syncthreads();

    if (tid < 48) {
        float a2 = b2[tid];
        const float* w2 = W2 + tid * 24;
        #pragma unroll
        for (int k = 0; k < 24; ++k) a2 += hidL[k] * w2[k];
        lg[tid] = a2;
        od_base[(long)b * ldl + tid] = a2;
    }

    float* prow = prev + ((long)b * E_ + i) * 768;
    float m = -3.4e38f;
    #pragma unroll
    for (int it = 0; it < 3; ++it) m = fmaxf(m, prow[tid + it * 256]);
    red[tid] = m; __syncthreads();
    for (int o = 128; o > 0; o >>= 1) { if (tid < o) red[tid] = fmaxf(red[tid], red[tid + o]); __syncthreads(); }
    float m0 = red[0];

    if (tid == 0) {      // first-max tie semantics (matches jnp.argmax)
        float best = lg[0]; int bi = 0;
        for (int k2 = 1; k2 < K_; ++k2) { float v = lg[k2]; if (v > best) { best = v; bi = k2; } }
        s_oidx = bi;
    }
    __syncthreads();
    int oidx = s_oidx;
    bool empty0 = (m0 == 0.0f);
    bool cond = (oidx == 0) && empty0;         // (oidx < C) & (oidx == PAD) & empty
    if (cond) {
        #pragma unroll
        for (int it = 0; it < 3; ++it) prow[tid + it * 256] = xs[tid + it * 256];
    }
    __syncthreads();

    if (!do_final) return;

    // mfin = max(prev[b,i,:]) after the conditional update
    float mfin;
    if (cond) {
        float mx = -3.4e38f;
        #pragma unroll
        for (int it = 0; it < 3; ++it) mx = fmaxf(mx, xs[tid + it * 256]);
        red[tid] = mx; __syncthreads();
        for (int o = 128; o > 0; o >>= 1) { if (tid < o) red[tid] = fmaxf(red[tid], red[tid + o]); __syncthreads(); }
        mfin = red[0];
    } else {
        mfin = m0;
    }

    // pred = pick(oidx) (AFTER cond update) -> stage in LDS (src may be prow)
    const float* src;
    if (oidx < C_)            src = pcb + (long)oidx * 768;
    else if (oidx < C_ + M_)  src = pnb + ((long)b * M_ + (oidx - C_)) * 768;
    else                      src = prev + ((long)b * E_ + (oidx - C_ - M_)) * 768;
    #pragma unroll
    for (int it = 0; it < 3; ++it) ps[tid + it * 256] = src[tid + it * 256];
    __syncthreads();

    if (mfin == 0.0f) {
        #pragma unroll
        for (int it = 0; it < 3; ++it) prow[tid + it * 256] = ps[tid + it * 256];
    }
}

// Build num_vec: for (b,m) find first/last position with number_mask==m+1
__global__ void k_numvec(const float* __restrict__ inp, const int* __restrict__ nmask,
                         float* __restrict__ numvec)
{
    int b = blockIdx.x / M_, m = blockIdx.x % M_;
    int tid = threadIdx.x;
    int fmin = S_, lmax = -1;
    for (int s = tid; s < S_; s += 256) {
        if (nmask[b * S_ + s] == m + 1) {
            if (s < fmin) fmin = s;
            if (s > lmax) lmax = s;
        }
    }
    __shared__ int sf[256], sl[256];
    sf[tid] = fmin; sl[tid] = lmax; __syncthreads();
    for (int o = 128; o > 0; o >>= 1) {
        if (tid < o) {
            sf[tid] = min(sf[tid], sf[tid + o]);
            sl[tid] = max(sl[tid], sl[tid + o]);
        }
        __syncthreads();
    }
    int first = sf[0], last = sl[0];
    bool exists = (last >= 0);
    if (!exists) { first = 0; last = 0; }
    const float* fv = inp + ((long)b * S_ + first) * H_;
    const float* lv = inp + ((long)b * S_ + last) * H_;
    float* dst = numvec + ((long)b * M_ + m) * H2_;
    for (int h = tid; h < H_; h += 256) {
        dst[h]      = exists ? fv[h] : 0.f;
        dst[H_ + h] = exists ? lv[h] : 0.f;
    }
}

__global__ void k_copy_cv(const float* __restrict__ inp, float* __restrict__ cvv)
{
    int b = blockIdx.x;
    for (int h = threadIdx.x; h < H_; h += 256)
        cvv[b * H_ + h] = inp[(long)b * S_ * H_ + h];
}

// ---------------------------------------------------------------------------
extern "C" void kernel_launch(void* const* d_in, const int* in_sizes, int n_in,
                              void* d_out, int out_size, void* d_ws, size_t ws_size,
                              hipStream_t stream)
{
    const float* inp    = (const float*)d_in[0];
    const int*   nmask  = (const int*)  d_in[3];
    const int*   gops   = (const int*)  d_in[4];
    const int*   gopd   = (const int*)  d_in[5];
    const float* constv = (const float*)d_in[6];
    const float* opv    = (const float*)d_in[7];
    const float* opj_W  = (const float*)d_in[8];
    const float* opj_b  = (const float*)d_in[9];
    const float* opj_g  = (const float*)d_in[10];
    const float* opj_be = (const float*)d_in[11];
    const float* odj_W  = (const float*)d_in[12];
    const float* odj_b  = (const float*)d_in[13];
    const float* odj_g  = (const float*)d_in[14];
    const float* odj_be = (const float*)d_in[15];
    const float* opc_W1 = (const float*)d_in[16];
    const float* opc_b1 = (const float*)d_in[17];
    const float* opc_W2 = (const float*)d_in[18];
    const float* opc_b2 = (const float*)d_in[19];
    const float* odc_W1 = (const float*)d_in[20];
    const float* odc_b1 = (const float*)d_in[21];
    const float* odc_W2 = (const float*)d_in[22];
    const float* odc_b2 = (const float*)d_in[23];
    const float* og_Wih = (const float*)d_in[24];
    const float* og_Whh = (const float*)d_in[25];
    const float* og_bih = (const float*)d_in[26];
    const float* og_bhh = (const float*)d_in[27];
    const float* cg_Wih = (const float*)d_in[28];
    const float* cg_Whh = (const float*)d_in[29];
    const float* cg_bih = (const float*)d_in[30];
    const float* cg_bhh = (const float*)d_in[31];

    float* op_out = (float*)d_out;                  // (B, E, OP)
    float* od_out = op_out + (long)B_ * E_ * OP_;   // (B, E, A, K)

    // workspace partition (floats), ~33 MB total (same as round 5)
    float* ws      = (float*)d_ws;
    float* num_vec = ws; ws += (long)B_ * M_ * H2_;       // 1.57M
    float* P       = ws; ws += (long)6 * 1024 * 768;      // 4.72M partials (shared)
    float* pn      = ws; ws += (long)B_ * M_ * H_;
    float* pcb     = ws; ws += (long)C_ * H_;
    float* gopv    = ws; ws += (long)B_ * E_ * H_;
    float* prev    = ws; ws += (long)B_ * E_ * H_;
    float* cv      = ws; ws += (long)B_ * H_;
    float* h0      = ws; ws += (long)B_ * H_;
    float* hx0     = ws; ws += (long)B_ * H_;
    float* hx1     = ws; ws += (long)B_ * H_;

    hipMemsetAsync(prev, 0, (size_t)B_ * E_ * H_ * sizeof(float), stream);

    // ---- preprocessing ----
    k_numvec<<<B_ * M_, 256, 0, stream>>>(inp, nmask, num_vec);

    // pn = LN(num_vec @ odj_W^T + odj_b)   M=1024, N=768, K=1536, KS=6 (nkt=8)
    k_proj_gemm<<<dim3(24, 16, 6), 64, 0, stream>>>(num_vec, H2_, nullptr, 1024,
                                                    odj_W, H2_, 8, P, H_, 1024);
    k_ln_finish<<<1024, 256, 0, stream>>>(P, H_, 1024, 6, odj_b, odj_g, odj_be, pn, H_);

    // pc = LN(const_vector @ odj_W^T + odj_b)   M=24 (padded to 64)
    k_proj_gemm<<<dim3(24, 1, 6), 64, 0, stream>>>(constv, H2_, nullptr, C_,
                                                   odj_W, H2_, 8, P, H_, 64);
    k_ln_finish<<<C_, 256, 0, stream>>>(P, H_, 64, 6, odj_b, odj_g, odj_be, pcb, H_);

    // gold_opv = LN(operator_vector[gold_operators] @ opj_W^T + opj_b)  M=512
    k_proj_gemm<<<dim3(24, 8, 6), 64, 0, stream>>>(opv, H2_, gops, 512,
                                                   opj_W, H2_, 8, P, H_, 512);
    k_ln_finish<<<512, 256, 0, stream>>>(P, H_, 512, 6, opj_b, opj_g, opj_be, gopv, H_);

    k_copy_cv<<<B_, 256, 0, stream>>>(inp, cv);

    // ---- decode loop ----
    const dim3 gg(144, 12);     // GRU GEMM: 1728 one-wave blocks
    const long ldE = (long)E_ * H_;

    for (int i = 0; i < E_; ++i) {
        if (i > 0) {
            const float* hrow = prev + (long)(i - 1) * H_;   // row stride E*H
            k_gru_gemm12<<<gg, 64, 0, stream>>>(cv, H_, 0, nullptr, 0, 0, nullptr, nullptr, nullptr,
                                                hrow, ldE, cg_Wih, cg_Whh, P);
            k_gru_finish12<<<192, 256, 0, stream>>>(P, hrow, ldE, cg_bih, cg_bhh, h0);
            k_gru_gemm12<<<gg, 64, 0, stream>>>(h0, H_, 0, nullptr, 0, 0, nullptr, nullptr, nullptr,
                                                hrow, ldE, cg_Wih + (long)G3_ * H_,
                                                cg_Whh + (long)G3_ * H_, P);
            k_gru_finish12<<<192, 256, 0, stream>>>(P, hrow, ldE, cg_bih + G3_, cg_bhh + G3_, cv);
        }
        // op head (fully fused)
        k_ophead_fused<<<B_, 256, 0, stream>>>(cv, opc_W1, opc_b1, opc_W2, opc_b2, op_out, i);

        for (int j = 0; j < A_; ++j) {
            const float* xptr; long ldx; int pickm;
            if (j == 0) { xptr = gopv + (long)i * H_; ldx = ldE; pickm = 0; }
            else        { xptr = nullptr; ldx = 0; pickm = 1; }
            const float* hp0 = (j == 0) ? cv : hx0;
            const float* hp1 = (j == 0) ? cv : hx1;

            k_gru_gemm12<<<gg, 64, 0, stream>>>(xptr, ldx, pickm, gopd, i, j - 1,
                                                pcb, pn, prev, hp0, H_,
                                                og_Wih, og_Whh, P);
            k_gru_finish12<<<192, 256, 0, stream>>>(P, hp0, H_, og_bih, og_bhh, hx0);
            k_gru_gemm12<<<gg, 64, 0, stream>>>(hx0, H_, 0, nullptr, 0, 0, nullptr, nullptr, nullptr,
                                                hp1, H_, og_Wih + (long)G3_ * H_,
                                                og_Whh + (long)G3_ * H_, P);
            k_gru_finish12<<<192, 256, 0, stream>>>(P, hp1, H_, og_bih + G3_, og_bhh + G3_, hx1);

            float* od_base = od_out + ((long)i * A_ + j) * K_;
            k_odhead<<<B_, 256, 0, stream>>>(hx1, odc_W1, odc_b1, odc_W2, odc_b2,
                                             od_base, (long)E_ * A_ * K_,
                                             prev, i, pcb, pn, (j == A_ - 1) ? 1 : 0);
        }
    }
}

// Round 7
// 1893.484 us; speedup vs baseline: 1.3011x; 1.3011x over previous
//
#include <hip/hip_runtime.h>
#include <math.h>

// Problem constants
constexpr int B_  = 64;
constexpr int S_  = 512;
constexpr int H_  = 768;
constexpr int H2_ = 1536;   // 2H
constexpr int G3_ = 2304;   // 3H
constexpr int OP_ = 18;
constexpr int C_  = 24;
constexpr int M_  = 16;
constexpr int E_  = 8;
constexpr int A_  = 3;
constexpr int K_  = 48;     // C+M+E
constexpr int HH_ = 384;    // H/2

using f32x4  = __attribute__((ext_vector_type(4))) float;
using short8 = __attribute__((ext_vector_type(8))) short;

#define MFMA16(a, b, c) __builtin_amdgcn_mfma_f32_16x16x32_bf16((a), (b), (c), 0, 0, 0)

// Split 8 f32 into bf16 hi (truncate) + bf16 lo (residual, truncate).
// hi+lo reconstructs ~17 mantissa bits; 3-term product error ~1e-5 rel.
__device__ __forceinline__ void cvt8(float4 p0, float4 p1, short8& hi, short8& lo)
{
    float x[8] = {p0.x, p0.y, p0.z, p0.w, p1.x, p1.y, p1.z, p1.w};
    #pragma unroll
    for (int e = 0; e < 8; ++e) {
        union { float f; unsigned u; } a; a.f = x[e];
        hi[e] = (short)(a.u >> 16);
        union { unsigned u; float f; } hb; hb.u = a.u & 0xffff0000u;
        union { float f; unsigned u; } r; r.f = x[e] - hb.f;
        lo[e] = (short)(r.u >> 16);
    }
}

// ---------------------------------------------------------------------------
// GRU dual GEMM via MFMA: grid(72) x 256 thr (4 waves).
// Block bx<36: gi cols [bx*64, +64) = x @ Wih^T ; bx>=36: gh = h @ Whh^T.
// Waves split K=768 into 4 ranges (6 k-tiles of 32 each), in-register accum,
// LDS reduce, wave 0 stores f32 to C[64][4608] (gi | gh). No partials in HBM.
// A-frag (16x32): lane: row=lane&15, k=(lane>>4)*8+e.  B-frag from W rows
// (B[k][n] = W[n][k]): same gather pattern on W. C/D: col=lane&15,
// row=(lane>>4)*4+reg  [verified layout, learn_hip m89].
// ---------------------------------------------------------------------------
__global__ __launch_bounds__(256) void k_gru_mfma(
    const float* __restrict__ x, long ldx, int pickmode,
    const int* __restrict__ gopd, int i, int jm1,
    const float* __restrict__ pcb, const float* __restrict__ pnb,
    const float* __restrict__ prevb,
    const float* __restrict__ h, long ldh,
    const float* __restrict__ Wih, const float* __restrict__ Whh,
    float* __restrict__ C)
{
    const int tid  = threadIdx.x;
    const int lane = tid & 63;
    const int w    = tid >> 6;
    const int bx   = blockIdx.x;
    const bool hside = bx >= 36;
    const int n0 = (hside ? bx - 36 : bx) * 64;
    const float* W = hside ? Whh : Wih;
    const int koff = (lane >> 4) * 8;

    // per-lane A row pointers (4 row-tiles), already offset by koff
    const float* arow[4];
    #pragma unroll
    for (int rt = 0; rt < 4; ++rt) {
        int r = rt * 16 + (lane & 15);
        const float* s;
        if (hside) s = h + (long)r * ldh;
        else if (!pickmode) s = x + (long)r * ldx;
        else {
            int idx = gopd[(r * E_ + i) * A_ + jm1];
            if (idx < C_)            s = pcb + (long)idx * H_;
            else if (idx < C_ + M_)  s = pnb + ((long)r * M_ + (idx - C_)) * H_;
            else                     s = prevb + ((long)r * E_ + (idx - C_ - M_)) * H_;
        }
        arow[rt] = s + koff;
    }
    const float* wrow[4];
    #pragma unroll
    for (int nt = 0; nt < 4; ++nt)
        wrow[nt] = W + (long)(n0 + nt * 16 + (lane & 15)) * H_ + koff;

    f32x4 acc[4][4];
    #pragma unroll
    for (int rt = 0; rt < 4; ++rt)
        #pragma unroll
        for (int nt = 0; nt < 4; ++nt) acc[rt][nt] = (f32x4){0.f, 0.f, 0.f, 0.f};

    for (int kt = w * 6; kt < w * 6 + 6; ++kt) {
        const int kb = kt * 32;
        short8 ah[4], al[4];
        #pragma unroll
        for (int rt = 0; rt < 4; ++rt) {
            float4 p0 = *(const float4*)(arow[rt] + kb);
            float4 p1 = *(const float4*)(arow[rt] + kb + 4);
            cvt8(p0, p1, ah[rt], al[rt]);
        }
        #pragma unroll
        for (int nt = 0; nt < 4; ++nt) {
            float4 q0 = *(const float4*)(wrow[nt] + kb);
            float4 q1 = *(const float4*)(wrow[nt] + kb + 4);
            short8 bh, bl;
            cvt8(q0, q1, bh, bl);
            #pragma unroll
            for (int rt = 0; rt < 4; ++rt) {
                acc[rt][nt] = MFMA16(ah[rt], bh, acc[rt][nt]);
                acc[rt][nt] = MFMA16(ah[rt], bl, acc[rt][nt]);
                acc[rt][nt] = MFMA16(al[rt], bh, acc[rt][nt]);
            }
        }
    }

    // cross-wave K reduction via LDS
    __shared__ f32x4 Lr[48][64];
    if (w > 0) {
        #pragma unroll
        for (int rt = 0; rt < 4; ++rt)
            #pragma unroll
            for (int nt = 0; nt < 4; ++nt)
                Lr[(w - 1) * 16 + rt * 4 + nt][lane] = acc[rt][nt];
    }
    __syncthreads();
    if (w == 0) {
        float* Cb = C + (hside ? 2304 : 0) + n0;
        #pragma unroll
        for (int rt = 0; rt < 4; ++rt)
            #pragma unroll
            for (int nt = 0; nt < 4; ++nt) {
                int f = rt * 4 + nt;
                f32x4 s = acc[rt][nt];
                s = s + Lr[f][lane] + Lr[16 + f][lane] + Lr[32 + f][lane];
                int col = nt * 16 + (lane & 15);
                int rb  = rt * 16 + ((lane >> 4) << 2);
                #pragma unroll
                for (int r = 0; r < 4; ++r)
                    Cb[(long)(rb + r) * 4608 + col] = s[r];
            }
    }
}

// ---------------------------------------------------------------------------
// Generic projection GEMM via MFMA: C[M x 768] = A[M x 1536] @ W^T.
// grid (12 colblocks, nrowblocks) x 256 thr; waves split 48 k-tiles 4 ways.
// ---------------------------------------------------------------------------
__global__ __launch_bounds__(256) void k_proj_mfma(
    const float* __restrict__ Ab, long lda, const int* __restrict__ gidx, int Mm,
    const float* __restrict__ W, int wld,
    float* __restrict__ C, int ldc)
{
    const int tid  = threadIdx.x;
    const int lane = tid & 63;
    const int w    = tid >> 6;
    const int n0 = blockIdx.x * 64;
    const int r0 = blockIdx.y * 64;
    const int koff = (lane >> 4) * 8;

    const float* arow[4];
    #pragma unroll
    for (int rt = 0; rt < 4; ++rt) {
        int r = r0 + rt * 16 + (lane & 15);
        int rr = r < Mm ? r : (Mm - 1);
        const float* s = gidx ? (Ab + (long)gidx[rr] * lda) : (Ab + (long)rr * lda);
        arow[rt] = s + koff;
    }
    const float* wrow[4];
    #pragma unroll
    for (int nt = 0; nt < 4; ++nt)
        wrow[nt] = W + (long)(n0 + nt * 16 + (lane & 15)) * wld + koff;

    f32x4 acc[4][4];
    #pragma unroll
    for (int rt = 0; rt < 4; ++rt)
        #pragma unroll
        for (int nt = 0; nt < 4; ++nt) acc[rt][nt] = (f32x4){0.f, 0.f, 0.f, 0.f};

    for (int kt = w * 12; kt < w * 12 + 12; ++kt) {
        const int kb = kt * 32;
        short8 ah[4], al[4];
        #pragma unroll
        for (int rt = 0; rt < 4; ++rt) {
            float4 p0 = *(const float4*)(arow[rt] + kb);
            float4 p1 = *(const float4*)(arow[rt] + kb + 4);
            cvt8(p0, p1, ah[rt], al[rt]);
        }
        #pragma unroll
        for (int nt = 0; nt < 4; ++nt) {
            float4 q0 = *(const float4*)(wrow[nt] + kb);
            float4 q1 = *(const float4*)(wrow[nt] + kb + 4);
            short8 bh, bl;
            cvt8(q0, q1, bh, bl);
            #pragma unroll
            for (int rt = 0; rt < 4; ++rt) {
                acc[rt][nt] = MFMA16(ah[rt], bh, acc[rt][nt]);
                acc[rt][nt] = MFMA16(ah[rt], bl, acc[rt][nt]);
                acc[rt][nt] = MFMA16(al[rt], bh, acc[rt][nt]);
            }
        }
    }

    __shared__ f32x4 Lr[48][64];
    if (w > 0) {
        #pragma unroll
        for (int rt = 0; rt < 4; ++rt)
            #pragma unroll
            for (int nt = 0; nt < 4; ++nt)
                Lr[(w - 1) * 16 + rt * 4 + nt][lane] = acc[rt][nt];
    }
    __syncthreads();
    if (w == 0) {
        #pragma unroll
        for (int rt = 0; rt < 4; ++rt)
            #pragma unroll
            for (int nt = 0; nt < 4; ++nt) {
                int f = rt * 4 + nt;
                f32x4 s = acc[rt][nt];
                s = s + Lr[f][lane] + Lr[16 + f][lane] + Lr[32 + f][lane];
                int col = n0 + nt * 16 + (lane & 15);
                int rb  = r0 + rt * 16 + ((lane >> 4) << 2);
                #pragma unroll
                for (int r = 0; r < 4; ++r)
                    if (rb + r < Mm) C[(long)(rb + r) * ldc + col] = s[r];
            }
    }
}

// Gates: read gi|gh (64x4608 raw), add biases, hnew = (1-z)*n + z*h
__global__ void k_gates2(const float* __restrict__ GI,
                         const float* __restrict__ h, long ldh,
                         const float* __restrict__ bih, const float* __restrict__ bhh,
                         float* __restrict__ hnew)
{
    int t = blockIdx.x * 256 + threadIdx.x;       // 64*768
    int b = t / 768, c = t - b * 768;
    const float* gb = GI + (long)b * 4608;
    float ir  = gb[c]        + bih[c];
    float iz  = gb[768 + c]  + bih[768 + c];
    float in_ = gb[1536 + c] + bih[1536 + c];
    float hr  = gb[2304 + c] + bhh[c];
    float hz  = gb[3072 + c] + bhh[768 + c];
    float hn  = gb[3840 + c] + bhh[1536 + c];
    float r  = 1.f / (1.f + expf(-(ir + hr)));
    float z_ = 1.f / (1.f + expf(-(iz + hz)));
    float n  = tanhf(in_ + r * hn);
    float hp = h[(long)b * ldh + c];
    hnew[t] = (1.f - z_) * n + z_ * hp;
}

// Add bias then LayerNorm each 768-wide row of X in place.
__global__ void k_ln2(float* __restrict__ X, const float* __restrict__ bias,
                      const float* __restrict__ g, const float* __restrict__ be)
{
    int row = blockIdx.x, tid = threadIdx.x;
    __shared__ float red[256];
    float* xr = X + (long)row * 768;
    float v[3];
    #pragma unroll
    for (int it = 0; it < 3; ++it) {
        int c2 = tid + it * 256;
        v[it] = xr[c2] + bias[c2];
    }
    float s = v[0] + v[1] + v[2];
    red[tid] = s; __syncthreads();
    for (int o = 128; o > 0; o >>= 1) { if (tid < o) red[tid] += red[tid + o]; __syncthreads(); }
    float mu = red[0] / 768.f;
    __syncthreads();
    float vv = 0.f;
    #pragma unroll
    for (int it = 0; it < 3; ++it) { float d = v[it] - mu; vv += d * d; }
    red[tid] = vv; __syncthreads();
    for (int o = 128; o > 0; o >>= 1) { if (tid < o) red[tid] += red[tid + o]; __syncthreads(); }
    float inv = 1.f / sqrtf(red[0] / 768.f + 1e-5f);
    #pragma unroll
    for (int it = 0; it < 3; ++it) {
        int c2 = tid + it * 256;
        xr[c2] = (v[it] - mu) * inv * g[c2] + be[c2];
    }
}

// Fused op head: hid = relu(cv@W1^T+b1) (384), logits = hid@W2^T+b2 (18)
__global__ __launch_bounds__(256) void k_ophead_fused(
    const float* __restrict__ cv,
    const float* __restrict__ W1, const float* __restrict__ b1,
    const float* __restrict__ W2, const float* __restrict__ b2,
    float* __restrict__ op_out, int i)
{
    int b = blockIdx.x, tid = threadIdx.x;
    __shared__ float xs[768];
    __shared__ float hs[384];
    const float* xr = cv + (long)b * 768;
    #pragma unroll
    for (int it = 0; it < 3; ++it) xs[tid + it * 256] = xr[tid + it * 256];
    __syncthreads();

    for (int c = tid; c < 384; c += 256) {
        const float* wr = W1 + (long)c * 768;
        float acc = 0.f;
        #pragma unroll 8
        for (int k = 0; k < 768; k += 4) {
            float4 xv = *(const float4*)&xs[k];
            float4 wv = *(const float4*)(wr + k);
            acc += xv.x * wv.x + xv.y * wv.y + xv.z * wv.z + xv.w * wv.w;
        }
        hs[c] = fmaxf(acc + b1[c], 0.f);
    }
    __syncthreads();

    int c = tid >> 3, g = tid & 7;
    float acc = 0.f;
    if (c < OP_) {
        const float* wr = W2 + (long)c * HH_;
        #pragma unroll
        for (int t = 0; t < 12; ++t) {
            int k = (g + 8 * t) * 4;
            float4 xv = *(const float4*)&hs[k];
            float4 wv = *(const float4*)(wr + k);
            acc += xv.x * wv.x + xv.y * wv.y + xv.z * wv.z + xv.w * wv.w;
        }
    }
    acc += __shfl_xor(acc, 1);
    acc += __shfl_xor(acc, 2);
    acc += __shfl_xor(acc, 4);
    if (c < OP_ && g == 0)
        op_out[((long)b * E_ + i) * OP_ + c] = acc + b2[c];
}

// ---------------------------------------------------------------------------
// Fused od head: MLP1(relu) + MLP2 + logit write + argmax + prev cond-update.
// If do_final: also pred = pick(oidx) and the post-loop final prev update.
// ---------------------------------------------------------------------------
__global__ __launch_bounds__(256) void k_odhead(
    const float* __restrict__ hx1,
    const float* __restrict__ W1, const float* __restrict__ b1,
    const float* __restrict__ W2, const float* __restrict__ b2,
    float* __restrict__ od_base, long ldl,
    float* __restrict__ prev, int i,
    const float* __restrict__ pcb, const float* __restrict__ pnb,
    int do_final)
{
    int b = blockIdx.x, tid = threadIdx.x;
    __shared__ float xs[768];
    __shared__ float ps[768];
    __shared__ float hidL[24];
    __shared__ float lg[48];
    __shared__ float red[256];
    __shared__ int s_oidx;

    const float* xr = hx1 + (long)b * 768;
    #pragma unroll
    for (int it = 0; it < 3; ++it) xs[tid + it * 256] = xr[tid + it * 256];
    __syncthreads();

    int c = tid >> 3, g = tid & 7;
    float acc = 0.f;
    if (c < 24) {
        const float* wr = W1 + (long)c * 768;
        #pragma unroll
        for (int t = 0; t < 24; ++t) {
            int k = (g + 8 * t) * 4;
            float4 xv = *(const float4*)&xs[k];
            float4 wv = *(const float4*)(wr + k);
            acc += xv.x * wv.x + xv.y * wv.y + xv.z * wv.z + xv.w * wv.w;
        }
    }
    acc += __shfl_xor(acc, 1);
    acc += __shfl_xor(acc, 2);
    acc += __shfl_xor(acc, 4);
    if (c < 24 && g == 0) hidL[c] = fmaxf(acc + b1[c], 0.f);
    __syncthreads();

    if (tid < 48) {
        float a2 = b2[tid];
        const float* w2 = W2 + tid * 24;
        #pragma unroll
        for (int k = 0; k < 24; ++k) a2 += hidL[k] * w2[k];
        lg[tid] = a2;
        od_base[(long)b * ldl + tid] = a2;
    }

    float* prow = prev + ((long)b * E_ + i) * 768;
    float m = -3.4e38f;
    #pragma unroll
    for (int it = 0; it < 3; ++it) m = fmaxf(m, prow[tid + it * 256]);
    red[tid] = m; __syncthreads();
    for (int o = 128; o > 0; o >>= 1) { if (tid < o) red[tid] = fmaxf(red[tid], red[tid + o]); __syncthreads(); }
    float m0 = red[0];

    if (tid == 0) {      // first-max tie semantics (matches jnp.argmax)
        float best = lg[0]; int bi = 0;
        for (int k2 = 1; k2 < K_; ++k2) { float v = lg[k2]; if (v > best) { best = v; bi = k2; } }
        s_oidx = bi;
    }
    __syncthreads();
    int oidx = s_oidx;
    bool empty0 = (m0 == 0.0f);
    bool cond = (oidx == 0) && empty0;
    if (cond) {
        #pragma unroll
        for (int it = 0; it < 3; ++it) prow[tid + it * 256] = xs[tid + it * 256];
    }
    __syncthreads();

    if (!do_final) return;

    float mfin;
    if (cond) {
        float mx = -3.4e38f;
        #pragma unroll
        for (int it = 0; it < 3; ++it) mx = fmaxf(mx, xs[tid + it * 256]);
        red[tid] = mx; __syncthreads();
        for (int o = 128; o > 0; o >>= 1) { if (tid < o) red[tid] = fmaxf(red[tid], red[tid + o]); __syncthreads(); }
        mfin = red[0];
    } else {
        mfin = m0;
    }

    const float* src;
    if (oidx < C_)            src = pcb + (long)oidx * 768;
    else if (oidx < C_ + M_)  src = pnb + ((long)b * M_ + (oidx - C_)) * 768;
    else                      src = prev + ((long)b * E_ + (oidx - C_ - M_)) * 768;
    #pragma unroll
    for (int it = 0; it < 3; ++it) ps[tid + it * 256] = src[tid + it * 256];
    __syncthreads();

    if (mfin == 0.0f) {
        #pragma unroll
        for (int it = 0; it < 3; ++it) prow[tid + it * 256] = ps[tid + it * 256];
    }
}

// Build num_vec: for (b,m) find first/last position with number_mask==m+1
__global__ void k_numvec(const float* __restrict__ inp, const int* __restrict__ nmask,
                         float* __restrict__ numvec)
{
    int b = blockIdx.x / M_, m = blockIdx.x % M_;
    int tid = threadIdx.x;
    int fmin = S_, lmax = -1;
    for (int s = tid; s < S_; s += 256) {
        if (nmask[b * S_ + s] == m + 1) {
            if (s < fmin) fmin = s;
            if (s > lmax) lmax = s;
        }
    }
    __shared__ int sf[256], sl[256];
    sf[tid] = fmin; sl[tid] = lmax; __syncthreads();
    for (int o = 128; o > 0; o >>= 1) {
        if (tid < o) {
            sf[tid] = min(sf[tid], sf[tid + o]);
            sl[tid] = max(sl[tid], sl[tid + o]);
        }
        __syncthreads();
    }
    int first = sf[0], last = sl[0];
    bool exists = (last >= 0);
    if (!exists) { first = 0; last = 0; }
    const float* fv = inp + ((long)b * S_ + first) * H_;
    const float* lv = inp + ((long)b * S_ + last) * H_;
    float* dst = numvec + ((long)b * M_ + m) * H2_;
    for (int h = tid; h < H_; h += 256) {
        dst[h]      = exists ? fv[h] : 0.f;
        dst[H_ + h] = exists ? lv[h] : 0.f;
    }
}

__global__ void k_copy_cv(const float* __restrict__ inp, float* __restrict__ cvv)
{
    int b = blockIdx.x;
    for (int h = threadIdx.x; h < H_; h += 256)
        cvv[b * H_ + h] = inp[(long)b * S_ * H_ + h];
}

// ---------------------------------------------------------------------------
extern "C" void kernel_launch(void* const* d_in, const int* in_sizes, int n_in,
                              void* d_out, int out_size, void* d_ws, size_t ws_size,
                              hipStream_t stream)
{
    const float* inp    = (const float*)d_in[0];
    const int*   nmask  = (const int*)  d_in[3];
    const int*   gops   = (const int*)  d_in[4];
    const int*   gopd   = (const int*)  d_in[5];
    const float* constv = (const float*)d_in[6];
    const float* opv    = (const float*)d_in[7];
    const float* opj_W  = (const float*)d_in[8];
    const float* opj_b  = (const float*)d_in[9];
    const float* opj_g  = (const float*)d_in[10];
    const float* opj_be = (const float*)d_in[11];
    const float* odj_W  = (const float*)d_in[12];
    const float* odj_b  = (const float*)d_in[13];
    const float* odj_g  = (const float*)d_in[14];
    const float* odj_be = (const float*)d_in[15];
    const float* opc_W1 = (const float*)d_in[16];
    const float* opc_b1 = (const float*)d_in[17];
    const float* opc_W2 = (const float*)d_in[18];
    const float* opc_b2 = (const float*)d_in[19];
    const float* odc_W1 = (const float*)d_in[20];
    const float* odc_b1 = (const float*)d_in[21];
    const float* odc_W2 = (const float*)d_in[22];
    const float* odc_b2 = (const float*)d_in[23];
    const float* og_Wih = (const float*)d_in[24];
    const float* og_Whh = (const float*)d_in[25];
    const float* og_bih = (const float*)d_in[26];
    const float* og_bhh = (const float*)d_in[27];
    const float* cg_Wih = (const float*)d_in[28];
    const float* cg_Whh = (const float*)d_in[29];
    const float* cg_bih = (const float*)d_in[30];
    const float* cg_bhh = (const float*)d_in[31];

    float* op_out = (float*)d_out;                  // (B, E, OP)
    float* od_out = op_out + (long)B_ * E_ * OP_;   // (B, E, A, K)

    // workspace partition (floats), ~15 MB total
    float* ws      = (float*)d_ws;
    float* num_vec = ws; ws += (long)B_ * M_ * H2_;       // 1024x1536
    float* pn      = ws; ws += (long)B_ * M_ * H_;        // 1024x768
    float* pcb     = ws; ws += (long)64 * H_;             // 24 used (pad 64)
    float* gopv    = ws; ws += (long)B_ * E_ * H_;        // 512x768
    float* prev    = ws; ws += (long)B_ * E_ * H_;
    float* gigh    = ws; ws += (long)B_ * 4608;           // gi | gh
    float* cv      = ws; ws += (long)B_ * H_;
    float* h0      = ws; ws += (long)B_ * H_;
    float* hx0     = ws; ws += (long)B_ * H_;
    float* hx1     = ws; ws += (long)B_ * H_;

    hipMemsetAsync(prev, 0, (size_t)B_ * E_ * H_ * sizeof(float), stream);

    // ---- preprocessing ----
    k_numvec<<<B_ * M_, 256, 0, stream>>>(inp, nmask, num_vec);

    // pn = LN(num_vec @ odj_W^T + odj_b)
    k_proj_mfma<<<dim3(12, 16), 256, 0, stream>>>(num_vec, H2_, nullptr, 1024,
                                                  odj_W, H2_, pn, H_);
    k_ln2<<<1024, 256, 0, stream>>>(pn, odj_b, odj_g, odj_be);

    // pc = LN(const_vector @ odj_W^T + odj_b)
    k_proj_mfma<<<dim3(12, 1), 256, 0, stream>>>(constv, H2_, nullptr, C_,
                                                 odj_W, H2_, pcb, H_);
    k_ln2<<<C_, 256, 0, stream>>>(pcb, odj_b, odj_g, odj_be);

    // gold_opv = LN(operator_vector[gold_operators] @ opj_W^T + opj_b)
    k_proj_mfma<<<dim3(12, 8), 256, 0, stream>>>(opv, H2_, gops, 512,
                                                 opj_W, H2_, gopv, H_);
    k_ln2<<<512, 256, 0, stream>>>(gopv, opj_b, opj_g, opj_be);

    k_copy_cv<<<B_, 256, 0, stream>>>(inp, cv);

    // ---- decode loop ----
    const long ldE = (long)E_ * H_;

    for (int i = 0; i < E_; ++i) {
        if (i > 0) {
            const float* hrow = prev + (long)(i - 1) * H_;   // row stride E*H
            k_gru_mfma<<<72, 256, 0, stream>>>(cv, H_, 0, nullptr, 0, 0,
                                               nullptr, nullptr, nullptr,
                                               hrow, ldE, cg_Wih, cg_Whh, gigh);
            k_gates2<<<192, 256, 0, stream>>>(gigh, hrow, ldE, cg_bih, cg_bhh, h0);
            k_gru_mfma<<<72, 256, 0, stream>>>(h0, H_, 0, nullptr, 0, 0,
                                               nullptr, nullptr, nullptr,
                                               hrow, ldE, cg_Wih + (long)G3_ * H_,
                                               cg_Whh + (long)G3_ * H_, gigh);
            k_gates2<<<192, 256, 0, stream>>>(gigh, hrow, ldE, cg_bih + G3_, cg_bhh + G3_, cv);
        }
        // op head (fully fused)
        k_ophead_fused<<<B_, 256, 0, stream>>>(cv, opc_W1, opc_b1, opc_W2, opc_b2, op_out, i);

        for (int j = 0; j < A_; ++j) {
            const float* xptr; long ldx; int pickm;
            if (j == 0) { xptr = gopv + (long)i * H_; ldx = ldE; pickm = 0; }
            else        { xptr = nullptr; ldx = 0; pickm = 1; }
            const float* hp0 = (j == 0) ? cv : hx0;
            const float* hp1 = (j == 0) ? cv : hx1;

            k_gru_mfma<<<72, 256, 0, stream>>>(xptr, ldx, pickm, gopd, i, j - 1,
                                               pcb, pn, prev, hp0, H_,
                                               og_Wih, og_Whh, gigh);
            k_gates2<<<192, 256, 0, stream>>>(gigh, hp0, H_, og_bih, og_bhh, hx0);
            k_gru_mfma<<<72, 256, 0, stream>>>(hx0, H_, 0, nullptr, 0, 0,
                                               nullptr, nullptr, nullptr,
                                               hp1, H_, og_Wih + (long)G3_ * H_,
                                               og_Whh + (long)G3_ * H_, gigh);
            k_gates2<<<192, 256, 0, stream>>>(gigh, hp1, H_, og_bih + G3_, og_bhh + G3_, hx1);

            float* od_base = od_out + ((long)i * A_ + j) * K_;
            k_odhead<<<B_, 256, 0, stream>>>(hx1, odc_W1, odc_b1, odc_W2, odc_b2,
                                             od_base, (long)E_ * A_ * K_,
                                             prev, i, pcb, pn, (j == A_ - 1) ? 1 : 0);
        }
    }
}

// Round 8
// 1755.517 us; speedup vs baseline: 1.4034x; 1.0786x over previous
//
#include <hip/hip_runtime.h>
#include <math.h>

// Problem constants
constexpr int B_  = 64;
constexpr int S_  = 512;
constexpr int H_  = 768;
constexpr int H2_ = 1536;   // 2H
constexpr int G3_ = 2304;   // 3H
constexpr int OP_ = 18;
constexpr int C_  = 24;
constexpr int M_  = 16;
constexpr int E_  = 8;
constexpr int A_  = 3;
constexpr int K_  = 48;     // C+M+E
constexpr int HH_ = 384;    // H/2

using f32x4  = __attribute__((ext_vector_type(4))) float;
using short8 = __attribute__((ext_vector_type(8))) short;

#define MFMA16(a, b, c) __builtin_amdgcn_mfma_f32_16x16x32_bf16((a), (b), (c), 0, 0, 0)

// Split f32 into bf16 hi (truncate) + bf16 lo (residual, truncate).
__device__ __forceinline__ void split1(float x, short& h, short& l)
{
    union { float f; unsigned u; } a; a.f = x;
    h = (short)(a.u >> 16);
    union { unsigned u; float f; } hb; hb.u = a.u & 0xffff0000u;
    union { float f; unsigned u; } r; r.f = x - hb.f;
    l = (short)(r.u >> 16);
}

// Legacy in-register splitter (used only by proj A-side, runs once)
__device__ __forceinline__ void cvt8(float4 p0, float4 p1, short8& hi, short8& lo)
{
    float x[8] = {p0.x, p0.y, p0.z, p0.w, p1.x, p1.y, p1.z, p1.w};
    #pragma unroll
    for (int e = 0; e < 8; ++e) { short h, l; split1(x[e], h, l); hi[e] = h; lo[e] = l; }
}

// Bulk f32 -> bf16 hi/lo splitter (weights, once per launch)
__global__ void k_split4(const float* __restrict__ src, short* __restrict__ hi,
                         short* __restrict__ lo, int n4)
{
    int t = blockIdx.x * 256 + threadIdx.x;
    if (t >= n4) return;
    float4 v = ((const float4*)src)[t];
    float x[4] = {v.x, v.y, v.z, v.w};
    short h[4], l[4];
    #pragma unroll
    for (int e = 0; e < 4; ++e) split1(x[e], h[e], l[e]);
    ((short4*)hi)[t] = make_short4(h[0], h[1], h[2], h[3]);
    ((short4*)lo)[t] = make_short4(l[0], l[1], l[2], l[3]);
}

// ---------------------------------------------------------------------------
// GRU dual GEMM via MFMA, all operands pre-split bf16 hi/lo.
// grid(72) x 256 thr (4 waves). bx<36: gi cols = x @ Wih^T ; else gh.
// Waves split K=768 4 ways, in-register accum, LDS reduce, wave0 stores f32.
// 3-term: Ah*Bh + Ah*Bl + Al*Bh.
// ---------------------------------------------------------------------------
__global__ __launch_bounds__(256) void k_gru_mfma(
    const short* __restrict__ xhi, const short* __restrict__ xlo, long ldx, int pickmode,
    const int* __restrict__ gopd, int i, int jm1,
    const short* __restrict__ pchi, const short* __restrict__ pclo,
    const short* __restrict__ pnhi, const short* __restrict__ pnlo,
    const short* __restrict__ pvhi, const short* __restrict__ pvlo,
    const short* __restrict__ hhi, const short* __restrict__ hlo, long ldh,
    const short* __restrict__ Wih_hi, const short* __restrict__ Wih_lo,
    const short* __restrict__ Whh_hi, const short* __restrict__ Whh_lo,
    float* __restrict__ C)
{
    const int tid  = threadIdx.x;
    const int lane = tid & 63;
    const int w    = tid >> 6;
    const int bx   = blockIdx.x;
    const bool hside = bx >= 36;
    const int n0 = (hside ? bx - 36 : bx) * 64;
    const int koff = (lane >> 4) * 8;

    const short* ahi[4]; const short* alo[4];
    #pragma unroll
    for (int rt = 0; rt < 4; ++rt) {
        int r = rt * 16 + (lane & 15);
        long off;
        const short *bh_, *bl_;
        if (hside) { bh_ = hhi; bl_ = hlo; off = (long)r * ldh; }
        else if (!pickmode) { bh_ = xhi; bl_ = xlo; off = (long)r * ldx; }
        else {
            int idx = gopd[(r * E_ + i) * A_ + jm1];
            if (idx < C_)           { bh_ = pchi; bl_ = pclo; off = (long)idx * H_; }
            else if (idx < C_ + M_) { bh_ = pnhi; bl_ = pnlo; off = ((long)r * M_ + (idx - C_)) * H_; }
            else                    { bh_ = pvhi; bl_ = pvlo; off = ((long)r * E_ + (idx - C_ - M_)) * H_; }
        }
        ahi[rt] = bh_ + off + koff;
        alo[rt] = bl_ + off + koff;
    }
    const short* whi[4]; const short* wlo[4];
    const short* WH = hside ? Whh_hi : Wih_hi;
    const short* WL = hside ? Whh_lo : Wih_lo;
    #pragma unroll
    for (int nt = 0; nt < 4; ++nt) {
        long off = (long)(n0 + nt * 16 + (lane & 15)) * H_ + koff;
        whi[nt] = WH + off;
        wlo[nt] = WL + off;
    }

    f32x4 acc[4][4];
    #pragma unroll
    for (int rt = 0; rt < 4; ++rt)
        #pragma unroll
        for (int nt = 0; nt < 4; ++nt) acc[rt][nt] = (f32x4){0.f, 0.f, 0.f, 0.f};

    for (int kt = w * 6; kt < w * 6 + 6; ++kt) {
        const int kb = kt * 32;
        short8 Ah[4], Al[4];
        #pragma unroll
        for (int rt = 0; rt < 4; ++rt) {
            Ah[rt] = *(const short8*)(ahi[rt] + kb);
            Al[rt] = *(const short8*)(alo[rt] + kb);
        }
        #pragma unroll
        for (int nt = 0; nt < 4; ++nt) {
            short8 Bh = *(const short8*)(whi[nt] + kb);
            short8 Bl = *(const short8*)(wlo[nt] + kb);
            #pragma unroll
            for (int rt = 0; rt < 4; ++rt) {
                acc[rt][nt] = MFMA16(Ah[rt], Bh, acc[rt][nt]);
                acc[rt][nt] = MFMA16(Ah[rt], Bl, acc[rt][nt]);
                acc[rt][nt] = MFMA16(Al[rt], Bh, acc[rt][nt]);
            }
        }
    }

    __shared__ f32x4 Lr[48][64];
    if (w > 0) {
        #pragma unroll
        for (int rt = 0; rt < 4; ++rt)
            #pragma unroll
            for (int nt = 0; nt < 4; ++nt)
                Lr[(w - 1) * 16 + rt * 4 + nt][lane] = acc[rt][nt];
    }
    __syncthreads();
    if (w == 0) {
        float* Cb = C + (hside ? 2304 : 0) + n0;
        #pragma unroll
        for (int rt = 0; rt < 4; ++rt)
            #pragma unroll
            for (int nt = 0; nt < 4; ++nt) {
                int f = rt * 4 + nt;
                f32x4 s = acc[rt][nt];
                s = s + Lr[f][lane] + Lr[16 + f][lane] + Lr[32 + f][lane];
                int col = nt * 16 + (lane & 15);
                int rb  = rt * 16 + ((lane >> 4) << 2);
                #pragma unroll
                for (int r = 0; r < 4; ++r)
                    Cb[(long)(rb + r) * 4608 + col] = s[r];
            }
    }
}

// ---------------------------------------------------------------------------
// Projection GEMM: A f32 (cvt in-reg, runs once), W pre-split bf16.
// grid (12 colblocks, nrowblocks) x 256 thr; waves split 48 k-tiles 4 ways.
// ---------------------------------------------------------------------------
__global__ __launch_bounds__(256) void k_proj_mfma(
    const float* __restrict__ Ab, long lda, const int* __restrict__ gidx, int Mm,
    const short* __restrict__ Whi, const short* __restrict__ Wlo, int wld,
    float* __restrict__ C, int ldc)
{
    const int tid  = threadIdx.x;
    const int lane = tid & 63;
    const int w    = tid >> 6;
    const int n0 = blockIdx.x * 64;
    const int r0 = blockIdx.y * 64;
    const int koff = (lane >> 4) * 8;

    const float* arow[4];
    #pragma unroll
    for (int rt = 0; rt < 4; ++rt) {
        int r = r0 + rt * 16 + (lane & 15);
        int rr = r < Mm ? r : (Mm - 1);
        const float* s = gidx ? (Ab + (long)gidx[rr] * lda) : (Ab + (long)rr * lda);
        arow[rt] = s + koff;
    }
    const short* whi[4]; const short* wlo[4];
    #pragma unroll
    for (int nt = 0; nt < 4; ++nt) {
        long off = (long)(n0 + nt * 16 + (lane & 15)) * wld + koff;
        whi[nt] = Whi + off; wlo[nt] = Wlo + off;
    }

    f32x4 acc[4][4];
    #pragma unroll
    for (int rt = 0; rt < 4; ++rt)
        #pragma unroll
        for (int nt = 0; nt < 4; ++nt) acc[rt][nt] = (f32x4){0.f, 0.f, 0.f, 0.f};

    for (int kt = w * 12; kt < w * 12 + 12; ++kt) {
        const int kb = kt * 32;
        short8 ah[4], al[4];
        #pragma unroll
        for (int rt = 0; rt < 4; ++rt) {
            float4 p0 = *(const float4*)(arow[rt] + kb);
            float4 p1 = *(const float4*)(arow[rt] + kb + 4);
            cvt8(p0, p1, ah[rt], al[rt]);
        }
        #pragma unroll
        for (int nt = 0; nt < 4; ++nt) {
            short8 Bh = *(const short8*)(whi[nt] + kb);
            short8 Bl = *(const short8*)(wlo[nt] + kb);
            #pragma unroll
            for (int rt = 0; rt < 4; ++rt) {
                acc[rt][nt] = MFMA16(ah[rt], Bh, acc[rt][nt]);
                acc[rt][nt] = MFMA16(ah[rt], Bl, acc[rt][nt]);
                acc[rt][nt] = MFMA16(al[rt], Bh, acc[rt][nt]);
            }
        }
    }

    __shared__ f32x4 Lr[48][64];
    if (w > 0) {
        #pragma unroll
        for (int rt = 0; rt < 4; ++rt)
            #pragma unroll
            for (int nt = 0; nt < 4; ++nt)
                Lr[(w - 1) * 16 + rt * 4 + nt][lane] = acc[rt][nt];
    }
    __syncthreads();
    if (w == 0) {
        #pragma unroll
        for (int rt = 0; rt < 4; ++rt)
            #pragma unroll
            for (int nt = 0; nt < 4; ++nt) {
                int f = rt * 4 + nt;
                f32x4 s = acc[rt][nt];
                s = s + Lr[f][lane] + Lr[16 + f][lane] + Lr[32 + f][lane];
                int col = n0 + nt * 16 + (lane & 15);
                int rb  = r0 + rt * 16 + ((lane >> 4) << 2);
                #pragma unroll
                for (int r = 0; r < 4; ++r)
                    if (rb + r < Mm) C[(long)(rb + r) * ldc + col] = s[r];
            }
    }
}

// Gates: read gi|gh (64x4608 raw), add biases, hnew = (1-z)*n + z*h  (+ shadow)
__global__ void k_gates2(const float* __restrict__ GI,
                         const float* __restrict__ h, long ldh,
                         const float* __restrict__ bih, const float* __restrict__ bhh,
                         float* __restrict__ hnew,
                         short* __restrict__ hnhi, short* __restrict__ hnlo)
{
    int t = blockIdx.x * 256 + threadIdx.x;       // 64*768
    int b = t / 768, c = t - b * 768;
    const float* gb = GI + (long)b * 4608;
    float ir  = gb[c]        + bih[c];
    float iz  = gb[768 + c]  + bih[768 + c];
    float in_ = gb[1536 + c] + bih[1536 + c];
    float hr  = gb[2304 + c] + bhh[c];
    float hz  = gb[3072 + c] + bhh[768 + c];
    float hn  = gb[3840 + c] + bhh[1536 + c];
    float r  = 1.f / (1.f + expf(-(ir + hr)));
    float z_ = 1.f / (1.f + expf(-(iz + hz)));
    float n  = tanhf(in_ + r * hn);
    float hp = h[(long)b * ldh + c];
    float v = (1.f - z_) * n + z_ * hp;
    hnew[t] = v;
    short sh, sl; split1(v, sh, sl);
    hnhi[t] = sh; hnlo[t] = sl;
}

// Add bias then LayerNorm each 768-wide row of X in place (+ shadow).
__global__ void k_ln2(float* __restrict__ X, const float* __restrict__ bias,
                      const float* __restrict__ g, const float* __restrict__ be,
                      short* __restrict__ Xhi, short* __restrict__ Xlo)
{
    int row = blockIdx.x, tid = threadIdx.x;
    __shared__ float red[256];
    float* xr = X + (long)row * 768;
    float v[3];
    #pragma unroll
    for (int it = 0; it < 3; ++it) {
        int c2 = tid + it * 256;
        v[it] = xr[c2] + bias[c2];
    }
    float s = v[0] + v[1] + v[2];
    red[tid] = s; __syncthreads();
    for (int o = 128; o > 0; o >>= 1) { if (tid < o) red[tid] += red[tid + o]; __syncthreads(); }
    float mu = red[0] / 768.f;
    __syncthreads();
    float vv = 0.f;
    #pragma unroll
    for (int it = 0; it < 3; ++it) { float d = v[it] - mu; vv += d * d; }
    red[tid] = vv; __syncthreads();
    for (int o = 128; o > 0; o >>= 1) { if (tid < o) red[tid] += red[tid + o]; __syncthreads(); }
    float inv = 1.f / sqrtf(red[0] / 768.f + 1e-5f);
    #pragma unroll
    for (int it = 0; it < 3; ++it) {
        int c2 = tid + it * 256;
        float o2 = (v[it] - mu) * inv * g[c2] + be[c2];
        xr[c2] = o2;
        short sh, sl; split1(o2, sh, sl);
        Xhi[(long)row * 768 + c2] = sh;
        Xlo[(long)row * 768 + c2] = sl;
    }
}

// Fused op head: hid = relu(cv@W1^T+b1) (384), logits = hid@W2^T+b2 (18)
__global__ __launch_bounds__(256) void k_ophead_fused(
    const float* __restrict__ cv,
    const float* __restrict__ W1, const float* __restrict__ b1,
    const float* __restrict__ W2, const float* __restrict__ b2,
    float* __restrict__ op_out, int i)
{
    int b = blockIdx.x, tid = threadIdx.x;
    __shared__ float xs[768];
    __shared__ float hs[384];
    const float* xr = cv + (long)b * 768;
    #pragma unroll
    for (int it = 0; it < 3; ++it) xs[tid + it * 256] = xr[tid + it * 256];
    __syncthreads();

    for (int c = tid; c < 384; c += 256) {
        const float* wr = W1 + (long)c * 768;
        float acc = 0.f;
        #pragma unroll 8
        for (int k = 0; k < 768; k += 4) {
            float4 xv = *(const float4*)&xs[k];
            float4 wv = *(const float4*)(wr + k);
            acc += xv.x * wv.x + xv.y * wv.y + xv.z * wv.z + xv.w * wv.w;
        }
        hs[c] = fmaxf(acc + b1[c], 0.f);
    }
    __syncthreads();

    int c = tid >> 3, g = tid & 7;
    float acc = 0.f;
    if (c < OP_) {
        const float* wr = W2 + (long)c * HH_;
        #pragma unroll
        for (int t = 0; t < 12; ++t) {
            int k = (g + 8 * t) * 4;
            float4 xv = *(const float4*)&hs[k];
            float4 wv = *(const float4*)(wr + k);
            acc += xv.x * wv.x + xv.y * wv.y + xv.z * wv.z + xv.w * wv.w;
        }
    }
    acc += __shfl_xor(acc, 1);
    acc += __shfl_xor(acc, 2);
    acc += __shfl_xor(acc, 4);
    if (c < OP_ && g == 0)
        op_out[((long)b * E_ + i) * OP_ + c] = acc + b2[c];
}

// ---------------------------------------------------------------------------
// Fused od head: MLP1(relu) + MLP2 + logit write + argmax + prev cond-update.
// Maintains prev bf16 shadow. If do_final: pred pick + final prev update.
// ---------------------------------------------------------------------------
__global__ __launch_bounds__(256) void k_odhead(
    const float* __restrict__ hx1,
    const float* __restrict__ W1, const float* __restrict__ b1,
    const float* __restrict__ W2, const float* __restrict__ b2,
    float* __restrict__ od_base, long ldl,
    float* __restrict__ prev, int i,
    const float* __restrict__ pcb, const float* __restrict__ pnb,
    short* __restrict__ pvhi, short* __restrict__ pvlo,
    int do_final)
{
    int b = blockIdx.x, tid = threadIdx.x;
    __shared__ float xs[768];
    __shared__ float ps[768];
    __shared__ float hidL[24];
    __shared__ float lg[48];
    __shared__ float red[256];
    __shared__ int s_oidx;

    const float* xr = hx1 + (long)b * 768;
    #pragma unroll
    for (int it = 0; it < 3; ++it) xs[tid + it * 256] = xr[tid + it * 256];
    __syncthreads();

    int c = tid >> 3, g = tid & 7;
    float acc = 0.f;
    if (c < 24) {
        const float* wr = W1 + (long)c * 768;
        #pragma unroll
        for (int t = 0; t < 24; ++t) {
            int k = (g + 8 * t) * 4;
            float4 xv = *(const float4*)&xs[k];
            float4 wv = *(const float4*)(wr + k);
            acc += xv.x * wv.x + xv.y * wv.y + xv.z * wv.z + xv.w * wv.w;
        }
    }
    acc += __shfl_xor(acc, 1);
    acc += __shfl_xor(acc, 2);
    acc += __shfl_xor(acc, 4);
    if (c < 24 && g == 0) hidL[c] = fmaxf(acc + b1[c], 0.f);
    __syncthreads();

    if (tid < 48) {
        float a2 = b2[tid];
        const float* w2 = W2 + tid * 24;
        #pragma unroll
        for (int k = 0; k < 24; ++k) a2 += hidL[k] * w2[k];
        lg[tid] = a2;
        od_base[(long)b * ldl + tid] = a2;
    }

    long poff = ((long)b * E_ + i) * 768;
    float* prow = prev + poff;
    float m = -3.4e38f;
    #pragma unroll
    for (int it = 0; it < 3; ++it) m = fmaxf(m, prow[tid + it * 256]);
    red[tid] = m; __syncthreads();
    for (int o = 128; o > 0; o >>= 1) { if (tid < o) red[tid] = fmaxf(red[tid], red[tid + o]); __syncthreads(); }
    float m0 = red[0];

    if (tid == 0) {      // first-max tie semantics (matches jnp.argmax)
        float best = lg[0]; int bi = 0;
        for (int k2 = 1; k2 < K_; ++k2) { float v = lg[k2]; if (v > best) { best = v; bi = k2; } }
        s_oidx = bi;
    }
    __syncthreads();
    int oidx = s_oidx;
    bool empty0 = (m0 == 0.0f);
    bool cond = (oidx == 0) && empty0;
    if (cond) {
        #pragma unroll
        for (int it = 0; it < 3; ++it) {
            int c2 = tid + it * 256;
            float v = xs[c2];
            prow[c2] = v;
            short sh, sl; split1(v, sh, sl);
            pvhi[poff + c2] = sh; pvlo[poff + c2] = sl;
        }
    }
    __syncthreads();

    if (!do_final) return;

    float mfin;
    if (cond) {
        float mx = -3.4e38f;
        #pragma unroll
        for (int it = 0; it < 3; ++it) mx = fmaxf(mx, xs[tid + it * 256]);
        red[tid] = mx; __syncthreads();
        for (int o = 128; o > 0; o >>= 1) { if (tid < o) red[tid] = fmaxf(red[tid], red[tid + o]); __syncthreads(); }
        mfin = red[0];
    } else {
        mfin = m0;
    }

    const float* src;
    if (oidx < C_)            src = pcb + (long)oidx * 768;
    else if (oidx < C_ + M_)  src = pnb + ((long)b * M_ + (oidx - C_)) * 768;
    else                      src = prev + ((long)b * E_ + (oidx - C_ - M_)) * 768;
    #pragma unroll
    for (int it = 0; it < 3; ++it) ps[tid + it * 256] = src[tid + it * 256];
    __syncthreads();

    if (mfin == 0.0f) {
        #pragma unroll
        for (int it = 0; it < 3; ++it) {
            int c2 = tid + it * 256;
            float v = ps[c2];
            prow[c2] = v;
            short sh, sl; split1(v, sh, sl);
            pvhi[poff + c2] = sh; pvlo[poff + c2] = sl;
        }
    }
}

// Build num_vec: for (b,m) find first/last position with number_mask==m+1
__global__ void k_numvec(const float* __restrict__ inp, const int* __restrict__ nmask,
                         float* __restrict__ numvec)
{
    int b = blockIdx.x / M_, m = blockIdx.x % M_;
    int tid = threadIdx.x;
    int fmin = S_, lmax = -1;
    for (int s = tid; s < S_; s += 256) {
        if (nmask[b * S_ + s] == m + 1) {
            if (s < fmin) fmin = s;
            if (s > lmax) lmax = s;
        }
    }
    __shared__ int sf[256], sl[256];
    sf[tid] = fmin; sl[tid] = lmax; __syncthreads();
    for (int o = 128; o > 0; o >>= 1) {
        if (tid < o) {
            sf[tid] = min(sf[tid], sf[tid + o]);
            sl[tid] = max(sl[tid], sl[tid + o]);
        }
        __syncthreads();
    }
    int first = sf[0], last = sl[0];
    bool exists = (last >= 0);
    if (!exists) { first = 0; last = 0; }
    const float* fv = inp + ((long)b * S_ + first) * H_;
    const float* lv = inp + ((long)b * S_ + last) * H_;
    float* dst = numvec + ((long)b * M_ + m) * H2_;
    for (int h = tid; h < H_; h += 256) {
        dst[h]      = exists ? fv[h] : 0.f;
        dst[H_ + h] = exists ? lv[h] : 0.f;
    }
}

__global__ void k_copy_cv(const float* __restrict__ inp, float* __restrict__ cvv,
                          short* __restrict__ cvhi, short* __restrict__ cvlo)
{
    int b = blockIdx.x;
    for (int h = threadIdx.x; h < H_; h += 256) {
        float v = inp[(long)b * S_ * H_ + h];
        cvv[b * H_ + h] = v;
        short sh, sl; split1(v, sh, sl);
        cvhi[b * H_ + h] = sh; cvlo[b * H_ + h] = sl;
    }
}

// ---------------------------------------------------------------------------
extern "C" void kernel_launch(void* const* d_in, const int* in_sizes, int n_in,
                              void* d_out, int out_size, void* d_ws, size_t ws_size,
                              hipStream_t stream)
{
    const float* inp    = (const float*)d_in[0];
    const int*   nmask  = (const int*)  d_in[3];
    const int*   gops   = (const int*)  d_in[4];
    const int*   gopd   = (const int*)  d_in[5];
    const float* constv = (const float*)d_in[6];
    const float* opv    = (const float*)d_in[7];
    const float* opj_W  = (const float*)d_in[8];
    const float* opj_b  = (const float*)d_in[9];
    const float* opj_g  = (const float*)d_in[10];
    const float* opj_be = (const float*)d_in[11];
    const float* odj_W  = (const float*)d_in[12];
    const float* odj_b  = (const float*)d_in[13];
    const float* odj_g  = (const float*)d_in[14];
    const float* odj_be = (const float*)d_in[15];
    const float* opc_W1 = (const float*)d_in[16];
    const float* opc_b1 = (const float*)d_in[17];
    const float* opc_W2 = (const float*)d_in[18];
    const float* opc_b2 = (const float*)d_in[19];
    const float* odc_W1 = (const float*)d_in[20];
    const float* odc_b1 = (const float*)d_in[21];
    const float* odc_W2 = (const float*)d_in[22];
    const float* odc_b2 = (const float*)d_in[23];
    const float* og_Wih = (const float*)d_in[24];
    const float* og_Whh = (const float*)d_in[25];
    const float* og_bih = (const float*)d_in[26];
    const float* og_bhh = (const float*)d_in[27];
    const float* cg_Wih = (const float*)d_in[28];
    const float* cg_Whh = (const float*)d_in[29];
    const float* cg_bih = (const float*)d_in[30];
    const float* cg_bhh = (const float*)d_in[31];

    float* op_out = (float*)d_out;                  // (B, E, OP)
    float* od_out = op_out + (long)B_ * E_ * OP_;   // (B, E, A, K)

    // ---- workspace partition ----
    float* ws      = (float*)d_ws;
    float* num_vec = ws; ws += (long)B_ * M_ * H2_;       // 1024x1536
    float* pn      = ws; ws += (long)B_ * M_ * H_;        // 1024x768
    float* pcb     = ws; ws += (long)64 * H_;             // 24 used (pad 64)
    float* gopv    = ws; ws += (long)B_ * E_ * H_;        // 512x768
    float* prev    = ws; ws += (long)B_ * E_ * H_;
    float* gigh    = ws; ws += (long)B_ * 4608;           // gi | gh
    float* cv      = ws; ws += (long)B_ * H_;
    float* h0      = ws; ws += (long)B_ * H_;
    float* hx0     = ws; ws += (long)B_ * H_;
    float* hx1     = ws; ws += (long)B_ * H_;

    // bf16 hi/lo shadows (shorts; all sizes even)
    auto alloc_s = [&](long elems) -> short* {
        short* p = (short*)ws; ws += elems / 2; return p;
    };
    // weights
    const long nOG = (long)2 * G3_ * H_;   // 3,538,944
    short* og_ih_hi = alloc_s(nOG); short* og_ih_lo = alloc_s(nOG);
    short* og_hh_hi = alloc_s(nOG); short* og_hh_lo = alloc_s(nOG);
    short* cg_ih_hi = alloc_s(nOG); short* cg_ih_lo = alloc_s(nOG);
    short* cg_hh_hi = alloc_s(nOG); short* cg_hh_lo = alloc_s(nOG);
    const long nPJ = (long)H_ * H2_;       // 1,179,648
    short* odj_hi = alloc_s(nPJ); short* odj_lo = alloc_s(nPJ);
    short* opj_hi = alloc_s(nPJ); short* opj_lo = alloc_s(nPJ);
    // activations
    short* pn_hi  = alloc_s((long)B_ * M_ * H_); short* pn_lo  = alloc_s((long)B_ * M_ * H_);
    short* pc_hi  = alloc_s((long)64 * H_);      short* pc_lo  = alloc_s((long)64 * H_);
    short* gv_hi  = alloc_s((long)B_ * E_ * H_); short* gv_lo  = alloc_s((long)B_ * E_ * H_);
    short* pv_hi  = alloc_s((long)B_ * E_ * H_); short* pv_lo  = alloc_s((long)B_ * E_ * H_);
    short* cv_hi  = alloc_s((long)B_ * H_);      short* cv_lo  = alloc_s((long)B_ * H_);
    short* h0_hi  = alloc_s((long)B_ * H_);      short* h0_lo  = alloc_s((long)B_ * H_);
    short* hx0_hi = alloc_s((long)B_ * H_);      short* hx0_lo = alloc_s((long)B_ * H_);
    short* hx1_hi = alloc_s((long)B_ * H_);      short* hx1_lo = alloc_s((long)B_ * H_);

    hipMemsetAsync(prev, 0, (size_t)B_ * E_ * H_ * sizeof(float), stream);
    hipMemsetAsync(pv_hi, 0, (size_t)B_ * E_ * H_ * sizeof(short), stream);
    hipMemsetAsync(pv_lo, 0, (size_t)B_ * E_ * H_ * sizeof(short), stream);

    // ---- weight pre-split ----
    auto split = [&](const float* src, short* hi, short* lo, long n) {
        int n4 = (int)(n / 4);
        k_split4<<<(n4 + 255) / 256, 256, 0, stream>>>(src, hi, lo, n4);
    };
    split(og_Wih, og_ih_hi, og_ih_lo, nOG);
    split(og_Whh, og_hh_hi, og_hh_lo, nOG);
    split(cg_Wih, cg_ih_hi, cg_ih_lo, nOG);
    split(cg_Whh, cg_hh_hi, cg_hh_lo, nOG);
    split(odj_W,  odj_hi,  odj_lo,  nPJ);
    split(opj_W,  opj_hi,  opj_lo,  nPJ);

    // ---- preprocessing ----
    k_numvec<<<B_ * M_, 256, 0, stream>>>(inp, nmask, num_vec);

    k_proj_mfma<<<dim3(12, 16), 256, 0, stream>>>(num_vec, H2_, nullptr, 1024,
                                                  odj_hi, odj_lo, H2_, pn, H_);
    k_ln2<<<1024, 256, 0, stream>>>(pn, odj_b, odj_g, odj_be, pn_hi, pn_lo);

    k_proj_mfma<<<dim3(12, 1), 256, 0, stream>>>(constv, H2_, nullptr, C_,
                                                 odj_hi, odj_lo, H2_, pcb, H_);
    k_ln2<<<C_, 256, 0, stream>>>(pcb, odj_b, odj_g, odj_be, pc_hi, pc_lo);

    k_proj_mfma<<<dim3(12, 8), 256, 0, stream>>>(opv, H2_, gops, 512,
                                                 opj_hi, opj_lo, H2_, gopv, H_);
    k_ln2<<<512, 256, 0, stream>>>(gopv, opj_b, opj_g, opj_be, gv_hi, gv_lo);

    k_copy_cv<<<B_, 256, 0, stream>>>(inp, cv, cv_hi, cv_lo);

    // ---- decode loop ----
    const long ldE = (long)E_ * H_;
    const long lW  = (long)G3_ * H_;   // layer-1 weight offset

    for (int i = 0; i < E_; ++i) {
        if (i > 0) {
            const float* hrow = prev + (long)(i - 1) * H_;
            const short* hrhi = pv_hi + (long)(i - 1) * H_;
            const short* hrlo = pv_lo + (long)(i - 1) * H_;
            k_gru_mfma<<<72, 256, 0, stream>>>(cv_hi, cv_lo, H_, 0, nullptr, 0, 0,
                                               nullptr, nullptr, nullptr, nullptr, nullptr, nullptr,
                                               hrhi, hrlo, ldE,
                                               cg_ih_hi, cg_ih_lo, cg_hh_hi, cg_hh_lo, gigh);
            k_gates2<<<192, 256, 0, stream>>>(gigh, hrow, ldE, cg_bih, cg_bhh, h0, h0_hi, h0_lo);
            k_gru_mfma<<<72, 256, 0, stream>>>(h0_hi, h0_lo, H_, 0, nullptr, 0, 0,
                                               nullptr, nullptr, nullptr, nullptr, nullptr, nullptr,
                                               hrhi, hrlo, ldE,
                                               cg_ih_hi + lW, cg_ih_lo + lW,
                                               cg_hh_hi + lW, cg_hh_lo + lW, gigh);
            k_gates2<<<192, 256, 0, stream>>>(gigh, hrow, ldE, cg_bih + G3_, cg_bhh + G3_,
                                              cv, cv_hi, cv_lo);
        }
        k_ophead_fused<<<B_, 256, 0, stream>>>(cv, opc_W1, opc_b1, opc_W2, opc_b2, op_out, i);

        for (int j = 0; j < A_; ++j) {
            const short *xhi, *xlo; long ldx; int pickm;
            if (j == 0) { xhi = gv_hi + (long)i * H_; xlo = gv_lo + (long)i * H_; ldx = ldE; pickm = 0; }
            else        { xhi = nullptr; xlo = nullptr; ldx = 0; pickm = 1; }
            const float* hp0 = (j == 0) ? cv : hx0;
            const float* hp1 = (j == 0) ? cv : hx1;
            const short* hp0hi = (j == 0) ? cv_hi : hx0_hi;
            const short* hp0lo = (j == 0) ? cv_lo : hx0_lo;
            const short* hp1hi = (j == 0) ? cv_hi : hx1_hi;
            const short* hp1lo = (j == 0) ? cv_lo : hx1_lo;

            k_gru_mfma<<<72, 256, 0, stream>>>(xhi, xlo, ldx, pickm, gopd, i, j - 1,
                                               pc_hi, pc_lo, pn_hi, pn_lo, pv_hi, pv_lo,
                                               hp0hi, hp0lo, H_,
                                               og_ih_hi, og_ih_lo, og_hh_hi, og_hh_lo, gigh);
            k_gates2<<<192, 256, 0, stream>>>(gigh, hp0, H_, og_bih, og_bhh, hx0, hx0_hi, hx0_lo);
            k_gru_mfma<<<72, 256, 0, stream>>>(hx0_hi, hx0_lo, H_, 0, nullptr, 0, 0,
                                               nullptr, nullptr, nullptr, nullptr, nullptr, nullptr,
                                               hp1hi, hp1lo, H_,
                                               og_ih_hi + lW, og_ih_lo + lW,
                                               og_hh_hi + lW, og_hh_lo + lW, gigh);
            k_gates2<<<192, 256, 0, stream>>>(gigh, hp1, H_, og_bih + G3_, og_bhh + G3_,
                                              hx1, hx1_hi, hx1_lo);

            float* od_base = od_out + ((long)i * A_ + j) * K_;
            k_odhead<<<B_, 256, 0, stream>>>(hx1, odc_W1, odc_b1, odc_W2, odc_b2,
                                             od_base, (long)E_ * A_ * K_,
                                             prev, i, pcb, pn, pv_hi, pv_lo,
                                             (j == A_ - 1) ? 1 : 0);
        }
    }
}